// Round 1
// baseline (11.138 us; speedup 1.0000x reference)
//
#include <hip/hip_runtime.h>
#include <hip/hip_bf16.h>

// out[b][o] = relu( bias[o] + sum_{s=0}^{4} W[o][s*1024 + loc[b][s]] )
// B=16384, SLOTS=5, ACTION_SIZE=1024, OUT=16, W is [16, 5120] row-major fp32.
//
// One thread per output element: t = b*16 + o. loc loads broadcast across the
// 16 threads sharing a row (L1), W gathers are L2-resident (W = 320 KB),
// output store fully coalesced.

#define ACTION_SIZE 1024
#define SLOTS 5
#define OUT_CH 16
#define FAN_IN (SLOTS * ACTION_SIZE)

__global__ __launch_bounds__(256) void position_encode_kernel(
    const int* __restrict__ loc,   // [B, 5] int32
    const float* __restrict__ W,   // [16, 5120]
    const float* __restrict__ bias,// [16]
    float* __restrict__ out,       // [B, 16]
    int total)                     // B*16
{
    int t = blockIdx.x * 256 + threadIdx.x;
    if (t >= total) return;

    int row = t >> 4;        // batch index
    int o   = t & 15;        // output channel

    const int* l = loc + row * SLOTS;
    const float* wrow = W + o * FAN_IN;

    float acc = bias[o];
#pragma unroll
    for (int s = 0; s < SLOTS; ++s) {
        int idx = l[s];
        acc += wrow[s * ACTION_SIZE + idx];
    }
    out[t] = fmaxf(acc, 0.0f);
}

extern "C" void kernel_launch(void* const* d_in, const int* in_sizes, int n_in,
                              void* d_out, int out_size, void* d_ws, size_t ws_size,
                              hipStream_t stream) {
    const int*   loc  = (const int*)d_in[0];    // [B,5] int32
    const float* W    = (const float*)d_in[1];  // [16,5120]
    const float* bias = (const float*)d_in[2];  // [16]
    float* out = (float*)d_out;

    int total = out_size;                       // B*16 = 262144
    int blocks = (total + 255) / 256;
    hipLaunchKernelGGL(position_encode_kernel, dim3(blocks), dim3(256), 0, stream,
                       loc, W, bias, out, total);
}